// Round 14
// baseline (3379.879 us; speedup 1.0000x reference)
//
#include <hip/hip_runtime.h>
#include <hip/hip_fp16.h>

#define T_ 1000

typedef float v2f __attribute__((ext_vector_type(2)));
typedef __fp16 h2t __attribute__((ext_vector_type(2)));
typedef __fp16 h8v_t __attribute__((ext_vector_type(8)));

#if defined(__has_builtin)
#if __has_builtin(__builtin_amdgcn_fdot2)
#define HAS_FDOT2 1
#endif
#endif
#ifndef HAS_FDOT2
#define HAS_FDOT2 0
#endif

// barrier with LDS visibility but NO vmcnt drain (keeps prefetch/stores in flight)
#define REC_BARRIER() asm volatile("s_waitcnt lgkmcnt(0)\n\ts_barrier" ::: "memory")

__device__ __forceinline__ float sigf(float x) { return 1.0f / (1.0f + __expf(-x)); }
__device__ __forceinline__ float tanh_fast(float x) { return 1.0f - 2.0f / (1.0f + __expf(2.0f * x)); }
__device__ __forceinline__ float dot4(float4 a, float4 b) {
  return a.x * b.x + a.y * b.y + a.z * b.z + a.w * b.w;
}
__device__ __forceinline__ void pkfma(v2f& acc, float4 w, float4 v) {
  v2f wl; wl[0] = w.x; wl[1] = w.y;
  v2f wh; wh[0] = w.z; wh[1] = w.w;
  v2f vl; vl[0] = v.x; vl[1] = v.y;
  v2f vh; vh[0] = v.z; vh[1] = v.w;
  acc += wl * vl;
  acc += wh * vh;
}
__device__ __forceinline__ unsigned short f2bf(float f) {
  unsigned u = __float_as_uint(f);
  u = (u + 0x7fffu + ((u >> 16) & 1u)) >> 16;  // RNE
  return (unsigned short)u;
}
__device__ __forceinline__ float bf2f(unsigned short h) {
  return __uint_as_float(((unsigned)h) << 16);
}
__device__ __forceinline__ float4 bf4_to_f4(ushort4 u) {
  float4 r;
  r.x = bf2f(u.x); r.y = bf2f(u.y); r.z = bf2f(u.z); r.w = bf2f(u.w);
  return r;
}

__global__ void bail_kernel(float* out, int n) {
  for (int i = threadIdx.x; i < n; i += 256) out[i] = 0.0f;
}

// ---------------- LN stats: per row (mu, rs) ----------------
__global__ __launch_bounds__(256) void ln_stats_kernel(const float* __restrict__ x,
                                                       float* __restrict__ mu_arr,
                                                       float* __restrict__ rs_arr) {
  const int lane = threadIdx.x & 63;
  const int w = threadIdx.x >> 6;
  const long row = (long)blockIdx.x * 4 + w;
  float v = (lane < 40) ? x[row * 40 + lane] : 0.0f;
  float s1 = v, s2 = v * v;
  for (int m = 32; m; m >>= 1) {
    s1 += __shfl_xor(s1, m, 64);
    s2 += __shfl_xor(s2, m, 64);
  }
  if (lane == 0) {
    const float mu = s1 * (1.0f / 40.0f);
    const float var = s2 * (1.0f / 40.0f) - mu * mu;
    mu_arr[row] = mu;
    rs_arr[row] = rsqrtf(var + 1e-5f);
  }
}

// ---------------- xw0 chunk = LN(x)[slice] @ Wih0^T  (LN fused; f16 out) ----------------
__global__ __launch_bounds__(256, 2) void gemm_xw0(
    const float* __restrict__ x,
    const float* __restrict__ mu_arr, const float* __restrict__ rs_arr,
    const float* __restrict__ ln_g, const float* __restrict__ ln_b,
    const float* __restrict__ Wf, const float* __restrict__ Wb,
    __fp16* __restrict__ xwf, __fp16* __restrict__ xwb,
    int Tc, int t0f, int t0b) {
  __shared__ float As[64 * 44];
  __shared__ float Bs[128 * 44];
  const int tid = threadIdx.x;
  const int tx = tid & 15, ty = tid >> 4;
  const int r0 = blockIdx.x * 64;
  const int jt = blockIdx.y;
  const int dir = jt >> 2, nh = jt & 3;
  const float* __restrict__ W = dir ? Wb : Wf;
  __fp16* __restrict__ out = dir ? xwb : xwf;
  const int jbase = nh * 128;
  const int t0 = dir ? t0b : t0f;

  float4* As4 = (float4*)As;
  float4* Bs4 = (float4*)Bs;
  {  // A stage with fused LayerNorm: 4 threads per row
    const int row = tid >> 2;
    const int t4 = tid & 3;
    const int r = r0 + row;
    const int br = r / Tc;
    const long xrow = (long)br * T_ + t0 + (r - br * Tc);
    const float mu = mu_arr[xrow];
    const float rs = rs_arr[xrow];
#pragma unroll
    for (int m = 0; m < 3; ++m) {
      const int k4 = t4 + m * 4;
      if (k4 < 10) {
        const float4 v = *(const float4*)&x[xrow * 40 + k4 * 4];
        const float4 g4 = *(const float4*)&ln_g[k4 * 4];
        const float4 b4 = *(const float4*)&ln_b[k4 * 4];
        float4 xn;
        xn.x = (v.x - mu) * rs * g4.x + b4.x;
        xn.y = (v.y - mu) * rs * g4.y + b4.y;
        xn.z = (v.z - mu) * rs * g4.z + b4.z;
        xn.w = (v.w - mu) * rs * g4.w + b4.w;
        As4[row * 11 + k4] = xn;
      }
    }
  }
  {  // B stage
    const int row = tid & 127;
    const int h = tid >> 7;
#pragma unroll
    for (int m = 0; m < 5; ++m) {
      const int k4 = h + m * 2;
      Bs4[row * 11 + k4] = *(const float4*)&W[(long)(jbase + row) * 40 + k4 * 4];
    }
  }
  __syncthreads();

  v2f acc2[4][8];
#pragma unroll
  for (int r = 0; r < 4; ++r)
#pragma unroll
    for (int c2 = 0; c2 < 8; ++c2) acc2[r][c2] = 0.0f;
#pragma unroll 1
  for (int k4 = 0; k4 < 10; ++k4) {
    float4 av[4];
#pragma unroll
    for (int r = 0; r < 4; ++r) av[r] = As4[(ty * 4 + r) * 11 + k4];
#pragma unroll
    for (int c2 = 0; c2 < 8; ++c2) {
      const float4 bv = Bs4[(tx + 16 * c2) * 11 + k4];
#pragma unroll
      for (int r = 0; r < 4; ++r) pkfma(acc2[r][c2], av[r], bv);
    }
  }
#pragma unroll
  for (int r = 0; r < 4; ++r) {
    const long ob = (long)(r0 + ty * 4 + r) * 512 + jbase + tx;
#pragma unroll
    for (int c2 = 0; c2 < 8; ++c2) out[ob + c2 * 16] = (__fp16)(acc2[r][c2][0] + acc2[r][c2][1]);
  }
}

// ---------------- Unified recurrence: quad-split, Whh f16 pairs in regs, f16 h in LDS ----------------
// lane: unit u = wave*16 + (lane>>2), k-quarter p = lane&3. Weights 64 VGPR (fits 128 cap,
// no AGPR movs). h kept in LDS as f16 pairs -> dot phase = 4 b128 reads + 64 fdot2, no cvt.
// Barrier = lgkmcnt(0)+s_barrier only (no vmcnt drain: prefetch/stores ride across steps).
__global__ __launch_bounds__(512) void rec_fused(
    const __fp16* __restrict__ xw_f, const __fp16* __restrict__ xw_b,
    const float* __restrict__ Whh_f, const float* __restrict__ Whh_b,
    const float* __restrict__ bih_f, const float* __restrict__ bhh_f,
    const float* __restrict__ bih_b, const float* __restrict__ bhh_b,
    float* __restrict__ h0out, unsigned short* __restrict__ h1out, int out_bf16,
    float* __restrict__ state, int Tc, int t0f, int t0b, int first) {
  const int tid = threadIdx.x;
  const int u = (tid >> 6) * 16 + ((tid & 63) >> 2);
  const int p = tid & 3;
  const int brow = blockIdx.x & 127;
  const int dir = blockIdx.x >> 7;
  const __fp16* __restrict__ xw = dir ? xw_b : xw_f;
  const float* __restrict__ Whh = dir ? Whh_b : Whh_f;
  const float* __restrict__ bih = dir ? bih_b : bih_f;
  const float* __restrict__ bhh = dir ? bhh_b : bhh_f;
  const int t0 = dir ? t0b : t0f;

  // f16-pair register weights: whp[g][ff*4+j] pairs with h16 chunk c4=(ff+p)&3,
  // covering k = p*32 + c4*8 + j*2 .. +2.
  h2t whp[4][16];
#pragma unroll
  for (int g = 0; g < 4; ++g) {
    const float4* wr4 = (const float4*)(Whh + (g * 128 + u) * 128);
#pragma unroll
    for (int ff = 0; ff < 4; ++ff) {
      const int c4 = (ff + p) & 3;
      const float4 wa = wr4[p * 8 + c4 * 2];
      const float4 wb = wr4[p * 8 + c4 * 2 + 1];
      h2t t0v; t0v[0] = (__fp16)wa.x; t0v[1] = (__fp16)wa.y;
      h2t t1v; t1v[0] = (__fp16)wa.z; t1v[1] = (__fp16)wa.w;
      h2t t2v; t2v[0] = (__fp16)wb.x; t2v[1] = (__fp16)wb.y;
      h2t t3v; t3v[0] = (__fp16)wb.z; t3v[1] = (__fp16)wb.w;
      whp[g][ff * 4 + 0] = t0v;
      whp[g][ff * 4 + 1] = t1v;
      whp[g][ff * 4 + 2] = t2v;
      whp[g][ff * 4 + 3] = t3v;
    }
  }
  const int myrow = p * 128 + u;
  const float bias_p = bih[myrow] + bhh[myrow];

  __shared__ h2t h16[2][64];           // f16 h state, parity double-buffered
  __shared__ float hring[2][8][128];   // f32 h output ring
  float* sblk = state + (long)blockIdx.x * 256;
  float c = 0.0f, hlast = 0.0f;
  if (first) {
    if (tid < 64) { h2t z; z[0] = (__fp16)0.0f; z[1] = (__fp16)0.0f; h16[0][tid] = z; }
  } else {
    if (tid < 64) {
      h2t pr; pr[0] = (__fp16)sblk[2 * tid]; pr[1] = (__fp16)sblk[2 * tid + 1];
      h16[0][tid] = pr;
    }
    c = sblk[128 + u];  // replicated per quad
  }
  const long gbase = (long)brow * Tc;
  float xr[8];
#pragma unroll
  for (int v = 0; v < 8; ++v) {
    xr[v] = 0.0f;
    if (v < Tc) {
      const int tr = dir ? (Tc - 1 - v) : v;
      xr[v] = (float)xw[(gbase + tr) * 512 + myrow];
    }
  }
  __syncthreads();

  const int nSB = (Tc + 7) / 8;
  const long obase = (long)brow * T_;
  for (int sb = 0; sb < nSB; ++sb) {
    const int rb = sb & 1;
#pragma unroll
    for (int su = 0; su < 8; ++su) {
      const int s = sb * 8 + su;
      if (s >= Tc) break;  // uniform
      const int rdq = su & 1, wrq = rdq ^ 1;
      if (su == 0 && sb > 0) {  // bulk store of previous (full) group
#pragma unroll
        for (int e = 0; e < 2; ++e) {
          const int idx = tid + e * 512;
          const int v = idx >> 7, j = idx & 127;
          const int s2 = (sb - 1) * 8 + v;
          const int tt = dir ? (Tc - 1 - s2) : s2;
          const long oidx = (obase + (t0 + tt)) * 256 + dir * 128 + j;
          const float hval = hring[rb ^ 1][v][j];
          if (out_bf16) h1out[oidx] = f2bf(hval);
          else          h0out[oidx] = hval;
        }
      }
      // ---- dot phase: 4 b128 LDS reads + 64 fdot2 ----
      float a0 = 0.f, a1 = 0.f, a2 = 0.f, a3 = 0.f;
      const h8v_t* hp = (const h8v_t*)h16[rdq];
#pragma unroll
      for (int ff = 0; ff < 4; ++ff) {
        const int c4 = (ff + p) & 3;
        const h8v_t hx = hp[p * 4 + c4];
        const h2t x0 = __builtin_shufflevector(hx, hx, 0, 1);
        const h2t x1 = __builtin_shufflevector(hx, hx, 2, 3);
        const h2t x2 = __builtin_shufflevector(hx, hx, 4, 5);
        const h2t x3 = __builtin_shufflevector(hx, hx, 6, 7);
#if HAS_FDOT2
        a0 = __builtin_amdgcn_fdot2(x0, whp[0][ff * 4 + 0], a0, false);
        a0 = __builtin_amdgcn_fdot2(x1, whp[0][ff * 4 + 1], a0, false);
        a0 = __builtin_amdgcn_fdot2(x2, whp[0][ff * 4 + 2], a0, false);
        a0 = __builtin_amdgcn_fdot2(x3, whp[0][ff * 4 + 3], a0, false);
        a1 = __builtin_amdgcn_fdot2(x0, whp[1][ff * 4 + 0], a1, false);
        a1 = __builtin_amdgcn_fdot2(x1, whp[1][ff * 4 + 1], a1, false);
        a1 = __builtin_amdgcn_fdot2(x2, whp[1][ff * 4 + 2], a1, false);
        a1 = __builtin_amdgcn_fdot2(x3, whp[1][ff * 4 + 3], a1, false);
        a2 = __builtin_amdgcn_fdot2(x0, whp[2][ff * 4 + 0], a2, false);
        a2 = __builtin_amdgcn_fdot2(x1, whp[2][ff * 4 + 1], a2, false);
        a2 = __builtin_amdgcn_fdot2(x2, whp[2][ff * 4 + 2], a2, false);
        a2 = __builtin_amdgcn_fdot2(x3, whp[2][ff * 4 + 3], a2, false);
        a3 = __builtin_amdgcn_fdot2(x0, whp[3][ff * 4 + 0], a3, false);
        a3 = __builtin_amdgcn_fdot2(x1, whp[3][ff * 4 + 1], a3, false);
        a3 = __builtin_amdgcn_fdot2(x2, whp[3][ff * 4 + 2], a3, false);
        a3 = __builtin_amdgcn_fdot2(x3, whp[3][ff * 4 + 3], a3, false);
#else
        const h2t xs[4] = {x0, x1, x2, x3};
#pragma unroll
        for (int j = 0; j < 4; ++j) {
          a0 = fmaf((float)xs[j][0], (float)whp[0][ff * 4 + j][0], a0);
          a0 = fmaf((float)xs[j][1], (float)whp[0][ff * 4 + j][1], a0);
          a1 = fmaf((float)xs[j][0], (float)whp[1][ff * 4 + j][0], a1);
          a1 = fmaf((float)xs[j][1], (float)whp[1][ff * 4 + j][1], a1);
          a2 = fmaf((float)xs[j][0], (float)whp[2][ff * 4 + j][0], a2);
          a2 = fmaf((float)xs[j][1], (float)whp[2][ff * 4 + j][1], a2);
          a3 = fmaf((float)xs[j][0], (float)whp[3][ff * 4 + j][0], a3);
          a3 = fmaf((float)xs[j][1], (float)whp[3][ff * 4 + j][1], a3);
        }
#endif
      }
      const float xin = xr[su] + bias_p;
      float pg0 = a0 + ((p == 0) ? xin : 0.0f);
      float pg1 = a1 + ((p == 1) ? xin : 0.0f);
      float pg2 = a2 + ((p == 2) ? xin : 0.0f);
      float pg3 = a3 + ((p == 3) ? xin : 0.0f);
      pg0 += __shfl_xor(pg0, 1, 64); pg0 += __shfl_xor(pg0, 2, 64);
      pg1 += __shfl_xor(pg1, 1, 64); pg1 += __shfl_xor(pg1, 2, 64);
      pg2 += __shfl_xor(pg2, 1, 64); pg2 += __shfl_xor(pg2, 2, 64);
      pg3 += __shfl_xor(pg3, 1, 64); pg3 += __shfl_xor(pg3, 2, 64);
      const float ig = sigf(pg0);
      const float fg = sigf(pg1);
      const float gg = tanh_fast(pg2);
      const float og = sigf(pg3);
      c = fg * c + ig * gg;
      const float hv2 = og * tanh_fast(c);
      if (p == 0) {
        ((__fp16*)h16[wrq])[u] = (__fp16)hv2;
        hring[rb][su][u] = hv2;
        hlast = hv2;
      }
      if (su == 7) {  // refill xw for next group
#pragma unroll
        for (int v = 0; v < 8; ++v) {
          const int sn = s + 1 + v;
          xr[v] = 0.0f;
          if (sn < Tc) {
            const int tr = dir ? (Tc - 1 - sn) : sn;
            xr[v] = (float)xw[(gbase + tr) * 512 + myrow];
          }
        }
      }
      REC_BARRIER();
    }
  }
  {  // final (possibly partial) group store
    const int sbL = (Tc - 1) >> 3;
    const int cnt = Tc - sbL * 8;
    const int rbL = sbL & 1;
#pragma unroll
    for (int e = 0; e < 2; ++e) {
      const int idx = tid + e * 512;
      const int v = idx >> 7, j = idx & 127;
      if (v < cnt) {
        const int s2 = sbL * 8 + v;
        const int tt = dir ? (Tc - 1 - s2) : s2;
        const long oidx = (obase + (t0 + tt)) * 256 + dir * 128 + j;
        const float hval = hring[rbL][v][j];
        if (out_bf16) h1out[oidx] = f2bf(hval);
        else          h0out[oidx] = hval;
      }
    }
  }
  if (p == 0) { sblk[u] = hlast; sblk[128 + u] = c; }
}

// ---------------- xw1 chunk GEMM: tile M=64 x N=128, K=256, micro 4x8, f16 out ----------------
__global__ __launch_bounds__(256, 2) void gemm_xw1(
    const float* __restrict__ h0,
    const float* __restrict__ Wf, const float* __restrict__ Wb,
    __fp16* __restrict__ xwf, __fp16* __restrict__ xwb,
    int Tc, int t0f, int t0b) {
  __shared__ float As[64 * 36];
  __shared__ float Bs[128 * 36];
  __shared__ int rowbase[64];
  const int tid = threadIdx.x;
  const int tx = tid & 15, ty = tid >> 4;
  const int r0 = blockIdx.x * 64;
  const int jt = blockIdx.y;
  const int dir = jt >> 2;
  const int nh = jt & 3;
  const float* __restrict__ W = dir ? Wb : Wf;
  __fp16* __restrict__ out = dir ? xwb : xwf;
  const int jbase = nh * 128;
  const int t0 = dir ? t0b : t0f;

  if (tid < 64) {
    const int r = r0 + tid;
    const int br = r / Tc;
    rowbase[tid] = br * T_ + t0 + (r - br * Tc);
  }

  float4* As4 = (float4*)As;
  float4* Bs4 = (float4*)Bs;
  v2f acc2[4][8];
#pragma unroll
  for (int r = 0; r < 4; ++r)
#pragma unroll
    for (int c2 = 0; c2 < 8; ++c2) acc2[r][c2] = 0.0f;
#pragma unroll 1
  for (int kk = 0; kk < 8; ++kk) {
    __syncthreads();
#pragma unroll
    for (int i = 0; i < 2; ++i) {
      const int q = tid + i * 256;
      const int row = q >> 3, k4 = q & 7;
      As4[row * 9 + k4] = *(const float4*)&h0[(long)rowbase[row] * 256 + kk * 32 + k4 * 4];
    }
#pragma unroll
    for (int i = 0; i < 4; ++i) {
      const int q = tid + i * 256;
      const int row = q >> 3, k4 = q & 7;
      Bs4[row * 9 + k4] = *(const float4*)&W[(long)(jbase + row) * 256 + kk * 32 + k4 * 4];
    }
    __syncthreads();
#pragma unroll 1
    for (int k4 = 0; k4 < 8; ++k4) {
      float4 av[4];
#pragma unroll
      for (int r = 0; r < 4; ++r) av[r] = As4[(ty * 4 + r) * 9 + k4];
#pragma unroll
      for (int c2 = 0; c2 < 8; ++c2) {
        const float4 bv = Bs4[(tx + 16 * c2) * 9 + k4];
#pragma unroll
        for (int r = 0; r < 4; ++r) pkfma(acc2[r][c2], av[r], bv);
      }
    }
  }
#pragma unroll
  for (int r = 0; r < 4; ++r) {
    const long ob = (long)(r0 + ty * 4 + r) * 512 + jbase + tx;
#pragma unroll
    for (int c2 = 0; c2 < 8; ++c2) out[ob + c2 * 16] = (__fp16)(acc2[r][c2][0] + acc2[r][c2][1]);
  }
}

// ---------------- attention scores ----------------
__global__ __launch_bounds__(256, 2) void score_kernel(
    const unsigned short* __restrict__ h1b, const float* __restrict__ W1,
    const float* __restrict__ b1, const float* __restrict__ w2,
    float* __restrict__ scores) {
  __shared__ float As[64 * 36];
  __shared__ float Bs[128 * 36];
  const int tid = threadIdx.x;
  const int tx = tid & 15, ty = tid >> 4;
  const long r0 = (long)blockIdx.x * 64;

  float4* As4 = (float4*)As;
  float4* Bs4 = (float4*)Bs;
  v2f acc2[4][8];
#pragma unroll
  for (int r = 0; r < 4; ++r)
#pragma unroll
    for (int c2 = 0; c2 < 8; ++c2) acc2[r][c2] = 0.0f;
#pragma unroll 1
  for (int kk = 0; kk < 8; ++kk) {
    __syncthreads();
#pragma unroll
    for (int i = 0; i < 2; ++i) {
      const int q = tid + i * 256;
      const int row = q >> 3, k4 = q & 7;
      const ushort4 uv = *(const ushort4*)&h1b[(r0 + row) * 256 + kk * 32 + k4 * 4];
      As4[row * 9 + k4] = bf4_to_f4(uv);
    }
#pragma unroll
    for (int i = 0; i < 4; ++i) {
      const int q = tid + i * 256;
      const int row = q >> 3, k4 = q & 7;
      Bs4[row * 9 + k4] = *(const float4*)&W1[(long)row * 256 + kk * 32 + k4 * 4];
    }
    __syncthreads();
#pragma unroll 1
    for (int k4 = 0; k4 < 8; ++k4) {
      float4 av[4];
#pragma unroll
      for (int r = 0; r < 4; ++r) av[r] = As4[(ty * 4 + r) * 9 + k4];
#pragma unroll
      for (int c2 = 0; c2 < 8; ++c2) {
        const float4 bv = Bs4[(tx + 16 * c2) * 9 + k4];
#pragma unroll
        for (int r = 0; r < 4; ++r) pkfma(acc2[r][c2], av[r], bv);
      }
    }
  }
#pragma unroll
  for (int r = 0; r < 4; ++r) {
    float s = 0.0f;
#pragma unroll
    for (int c2 = 0; c2 < 8; ++c2) {
      const int col = tx + 16 * c2;
      s += tanh_fast(acc2[r][c2][0] + acc2[r][c2][1] + b1[col]) * w2[col];
    }
#pragma unroll
    for (int m = 1; m < 16; m <<= 1) s += __shfl_xor(s, m, 16);
    if (tx == 0) scores[r0 + ty * 4 + r] = s;
  }
}

// ---------------- softmax over T + ctx + MLP head ----------------
__global__ __launch_bounds__(256, 2) void head_kernel(
    const float* __restrict__ scores, const unsigned short* __restrict__ h1b,
    const float* __restrict__ fW1, const float* __restrict__ fb1,
    const float* __restrict__ fW2, const float* __restrict__ fb2,
    float* __restrict__ outp) {
  const int b = blockIdx.x, tid = threadIdx.x;
  __shared__ float wls[1000];
  __shared__ float red[8];
  __shared__ __align__(16) float ctx[256];
  __shared__ __align__(16) float hid[128];

  float sv[4];
  float mx = -1e30f;
#pragma unroll
  for (int i = 0; i < 4; ++i) {
    const int t = tid + i * 256;
    sv[i] = (t < 1000) ? scores[b * 1000 + t] : -1e30f;
    mx = fmaxf(mx, sv[i]);
  }
  for (int m = 32; m; m >>= 1) mx = fmaxf(mx, __shfl_xor(mx, m, 64));
  if ((tid & 63) == 0) red[tid >> 6] = mx;
  __syncthreads();
  mx = fmaxf(fmaxf(red[0], red[1]), fmaxf(red[2], red[3]));
  float se = 0.0f;
#pragma unroll
  for (int i = 0; i < 4; ++i) {
    const int t = tid + i * 256;
    if (t < 1000) {
      const float e = __expf(sv[i] - mx);
      wls[t] = e;
      se += e;
    }
  }
  for (int m = 32; m; m >>= 1) se += __shfl_xor(se, m, 64);
  if ((tid & 63) == 0) red[4 + (tid >> 6)] = se;
  __syncthreads();
  const float rinv = 1.0f / (red[4] + red[5] + red[6] + red[7]);

  float a = 0.0f;
  const unsigned short* hb = h1b + (long)b * T_ * 256 + tid;
  for (int t = 0; t < T_; ++t) a = fmaf(wls[t], bf2f(hb[t * 256]), a);
  ctx[tid] = a * rinv;
  __syncthreads();
  if (tid < 128) {
    float s = fb1[tid];
    const float4* wr = (const float4*)&fW1[tid * 256];
    const float4* cc = (const float4*)ctx;
#pragma unroll
    for (int f = 0; f < 64; ++f) s += dot4(wr[f], cc[f]);
    hid[tid] = fmaxf(s, 0.0f);
  }
  __syncthreads();
  if (tid < 8) {
    float s = fb2[tid];
    const float4* wr = (const float4*)&fW2[tid * 128];
    const float4* hh = (const float4*)hid;
#pragma unroll
    for (int f = 0; f < 32; ++f) s += dot4(wr[f], hh[f]);
    outp[b * 8 + tid] = s;
  }
}

extern "C" void kernel_launch(void* const* d_in, const int* in_sizes, int n_in,
                              void* d_out, int out_size, void* d_ws, size_t ws_size,
                              hipStream_t stream) {
  (void)in_sizes; (void)n_in; (void)out_size;
  const float* x       = (const float*)d_in[0];
  const float* ln_g    = (const float*)d_in[1];
  const float* ln_b    = (const float*)d_in[2];
  const float* Wih_f0  = (const float*)d_in[3];
  const float* Whh_f0  = (const float*)d_in[4];
  const float* bih_f0  = (const float*)d_in[5];
  const float* bhh_f0  = (const float*)d_in[6];
  const float* Wih_b0  = (const float*)d_in[7];
  const float* Whh_b0  = (const float*)d_in[8];
  const float* bih_b0  = (const float*)d_in[9];
  const float* bhh_b0  = (const float*)d_in[10];
  const float* Wih_f1  = (const float*)d_in[11];
  const float* Whh_f1  = (const float*)d_in[12];
  const float* bih_f1  = (const float*)d_in[13];
  const float* bhh_f1  = (const float*)d_in[14];
  const float* Wih_b1  = (const float*)d_in[15];
  const float* Whh_b1  = (const float*)d_in[16];
  const float* bih_b1  = (const float*)d_in[17];
  const float* bhh_b1  = (const float*)d_in[18];
  const float* attn_W1 = (const float*)d_in[19];
  const float* attn_b1 = (const float*)d_in[20];
  const float* attn_w2 = (const float*)d_in[21];
  const float* fc_W1   = (const float*)d_in[22];
  const float* fc_b1   = (const float*)d_in[23];
  const float* fc_W2   = (const float*)d_in[24];
  const float* fc_b2   = (const float*)d_in[25];

  char* base = (char*)d_ws;
  size_t off = 0;
  auto alloc = [&](size_t bytes) {
    char* ptr = base + off;
    off += (bytes + 255) & ~(size_t)255;
    return ptr;
  };
  float*          h0    = (float*)alloc(32768000ull * 4);          // 131.1 MB
  unsigned short* h1b   = (unsigned short*)alloc(32768000ull * 2); //  65.5 MB
  float*          state = (float*)alloc(65536ull * 4);
  float*          scor  = (float*)alloc(128000ull * 4);
  float*          mu_a  = (float*)alloc(128000ull * 4);
  float*          rs_a  = (float*)alloc(128000ull * 4);

  const size_t rem = (ws_size > off) ? (ws_size - off) : 0;
  static const int cands[16] = {1000, 500, 250, 200, 125, 100, 50, 40, 25, 20, 10, 8, 5, 4, 2, 1};
  int Tc = 0;
  for (int ci = 0; ci < 16; ++ci) {
    // xw buffer: 65536 values/step/dir x 2 dirs x 2B (f16) = 262144 B per step
    if (262144ull * (size_t)cands[ci] <= rem) { Tc = cands[ci]; break; }
  }
  if (Tc == 0) {
    bail_kernel<<<dim3(1), dim3(256), 0, stream>>>((float*)d_out, 1024);
    return;
  }
  __fp16* xwf = (__fp16*)(base + off);
  __fp16* xwb = xwf + 65536L * Tc;

  ln_stats_kernel<<<dim3(32000), dim3(256), 0, stream>>>(x, mu_a, rs_a);
  const int nch = T_ / Tc;
  // Layer 0: xw0 chunk GEMM (LN fused) + recurrence
  for (int ch = 0; ch < nch; ++ch) {
    const int t0f = ch * Tc;
    const int t0b = T_ - (ch + 1) * Tc;
    gemm_xw0<<<dim3(2 * Tc, 8), dim3(256), 0, stream>>>(x, mu_a, rs_a, ln_g, ln_b,
                                                        Wih_f0, Wih_b0, xwf, xwb, Tc, t0f, t0b);
    rec_fused<<<dim3(256), dim3(512), 0, stream>>>(xwf, xwb, Whh_f0, Whh_b0,
                                                   bih_f0, bhh_f0, bih_b0, bhh_b0,
                                                   h0, h1b, 0, state, Tc, t0f, t0b,
                                                   (ch == 0) ? 1 : 0);
  }
  // Layer 1: xw1 chunk GEMM + recurrence (bf16 h1 out)
  for (int ch = 0; ch < nch; ++ch) {
    const int t0f = ch * Tc;
    const int t0b = T_ - (ch + 1) * Tc;
    gemm_xw1<<<dim3(2 * Tc, 8), dim3(256), 0, stream>>>(h0, Wih_f1, Wih_b1, xwf, xwb, Tc, t0f, t0b);
    rec_fused<<<dim3(256), dim3(512), 0, stream>>>(xwf, xwb, Whh_f1, Whh_b1,
                                                   bih_f1, bhh_f1, bih_b1, bhh_b1,
                                                   h0, h1b, 1, state, Tc, t0f, t0b,
                                                   (ch == 0) ? 1 : 0);
  }
  score_kernel<<<dim3(2000), dim3(256), 0, stream>>>(h1b, attn_W1, attn_b1, attn_w2, scor);
  head_kernel<<<dim3(128), dim3(256), 0, stream>>>(scor, h1b, fc_W1, fc_b1, fc_W2, fc_b2,
                                                   (float*)d_out);
}